// Round 3
// baseline (259.162 us; speedup 1.0000x reference)
//
#include <hip/hip_runtime.h>
#include <float.h>
#include <stdint.h>

#define BB 4
#define NN 20000
#define MM 1024
#define CAP 256
#define KSEL 50
#define NTILE 313            // ceil(NN/64)
#define GRID1 (NTILE * BB)   // 1252 blocks; co-residency: 5 blocks/CU x 256 = 1280 >= 1252
#define NODEBLK 1024         // node phase uses blocks 0..1023 (4 waves -> 1 node/wave)

typedef unsigned long long ull;

// order-preserving float -> uint32 map (total order incl. negatives)
__device__ __forceinline__ unsigned int fkey(float d) {
    unsigned int u = __float_as_uint(d);
    return (u & 0x80000000u) ? ~u : (u | 0x80000000u);
}
__device__ __forceinline__ float fkey_inv(unsigned int h) {
    return (h & 0x80000000u) ? __uint_as_float(h ^ 0x80000000u)
                             : __uint_as_float(~h);
}
__device__ __forceinline__ ull umin64(ull a, ull b) { return a < b ? a : b; }

// Fused assign + node kernel. Phase bodies are bit-identical to the R1
// 2-kernel version (measured best, absmax 0.0); the only change is replacing
// the kernel boundary (~4 us dispatch cost, measured via R2's +4.4 us for one
// added dispatch) with a device-wide ticket spin-barrier.
//
// Co-residency proof (spin-barrier cannot deadlock):
//   __launch_bounds__(256,5) -> VGPR <= 102 -> 5 waves/SIMD -> 5 blocks/CU
//   LDS 18.4 KB/block x 5 = 92 KB <= 160 KB ; waves 20 <= 32
//   capacity 5 x 256 CU = 1280 >= GRID1 = 1252  -> all blocks resident.
// Barrier counter starts at harness poison; baseline via *sent (same proven
// trick as cnt/done). Release: threadfence + agent-scope add. Acquire:
// agent-scope load + threadfence (invalidates L1/XCD-L2 for the CU).
__global__ __launch_bounds__(256, 5) void k_fused(
    const float* __restrict__ pts, const float* __restrict__ kp,
    const float* __restrict__ pose, const float* __restrict__ kpw,
    const float* __restrict__ ow, const unsigned int* __restrict__ sent,
    int* __restrict__ p2n, float4* __restrict__ pt4,
    unsigned int* __restrict__ cnt, int* __restrict__ lst,
    float* __restrict__ part, unsigned int* __restrict__ done,
    unsigned int* __restrict__ bar, float* __restrict__ out)
{
    // LDS union: phase1 {skp 16KB + skey 2KB}, phase3 {skeys 8KB + red/flag}
    __shared__ __align__(16) char smraw[18432];
    float4* skp = (float4*)smraw;                                       // ph1 [0,16384)
    ull (*skey)[64] = (ull (*)[64])(smraw + 16384);                     // ph1 [16384,18432)
    ull (*skeys)[CAP] = (ull (*)[CAP])smraw;                            // ph3 [0,8192)
    float* red = (float*)(smraw + 8192);                                // ph3 8 floats
    int* lastflag = (int*)(smraw + 8224);                               // ph3

    const unsigned int s0 = *sent;
    const int tid = threadIdx.x;
    const int w = tid >> 6, lane = tid & 63;

    // ---------------- phase 1: nearest-node assign (R1 k_assign body) ----
    {
        const int b    = blockIdx.x & 3;
        const int tile = blockIdx.x >> 2;

        for (int j = tid; j < MM; j += 256) {
            const float* kk = kp + ((size_t)b * MM + j) * 3;
            float x = kk[0], y = kk[1], z = kk[2];
            skp[j] = make_float4(-2.0f * x, -2.0f * y, -2.0f * z,
                                 x * x + y * y + z * z);   // (-2k, |k|^2)
        }
        __syncthreads();

        const int n = tile * 64 + lane;
        const bool v = n < NN;
        const float* pb = pts + (size_t)b * NN * 3;
        float px = 0.f, py = 0.f, pz = 0.f;
        if (v) { px = pb[n * 3]; py = pb[n * 3 + 1]; pz = pb[n * 3 + 2]; }

        float best = FLT_MAX;
        int bi = 0;
        const int j0 = w * 256;                 // wave's 256-kp sub-chunk
        #pragma unroll 8
        for (int j = 0; j < 256; ++j) {
            float4 q = skp[j0 + j];             // uniform broadcast ds_read_b128
            // d' = |k|^2 - 2*k.p : 3-fma chain, argmin-equiv (psq deferred)
            float d = fmaf(q.x, px, fmaf(q.y, py, fmaf(q.z, pz, q.w)));
            if (d < best) { best = d; bi = j0 + j; }   // strict <: first-min
        }
        skey[w][lane] = v ? (((ull)fkey(best) << 32) | (unsigned int)bi) : ~0ULL;
        __syncthreads();

        // wave 0 finishes point tile*64+tid (coords live in its own regs)
        if (tid < 64 && v) {
            ull kmin = skey[0][lane];
            #pragma unroll
            for (int ww = 1; ww < 4; ++ww) kmin = umin64(kmin, skey[ww][lane]);
            const int bi_g = (int)(unsigned int)(kmin & 0xFFFFFFFFULL);
            const float psq = fmaf(px, px, fmaf(py, py, pz * pz));
            const float bestd = fkey_inv((unsigned int)(kmin >> 32)) + psq;
            const float* P = pose + b * 16;
            float tx = P[0]*px + P[1]*py + P[2] *pz + P[3];
            float ty = P[4]*px + P[5]*py + P[6] *pz + P[7];
            float tz = P[8]*px + P[9]*py + P[10]*pz + P[11];
            const int g = b * NN + n;
            p2n[g] = bi_g;
            pt4[g] = make_float4(tx, ty, tz, bestd);
            const int node = b * MM + bi_g;
            unsigned int old = atomicAdd(&cnt[node], 1u);
            int s = (int)(old - s0);
            if (s >= 0 && s < CAP) lst[node * CAP + s] = n;
        }
    }

    // ---------------- device-wide barrier ----------------
    __syncthreads();                       // all ph1 LDS traffic done (smraw reuse)
    if (tid == 0) {
        __threadfence();                   // release: ph1 writes -> coherence point
        __hip_atomic_fetch_add(bar, 1u, __ATOMIC_RELEASE, __HIP_MEMORY_SCOPE_AGENT);
        while ((unsigned int)(__hip_atomic_load(bar, __ATOMIC_ACQUIRE,
                                                __HIP_MEMORY_SCOPE_AGENT) - s0) < GRID1)
            __builtin_amdgcn_s_sleep(8);
        __threadfence();                   // acquire: invalidate stale cache lines
    }
    __syncthreads();

    if (blockIdx.x >= NODEBLK) return;     // extra ph1 blocks exit after arriving

    // ---------------- phase 3: per-node knn-mean + reduce (R1 k_node body) --
    const int node = blockIdx.x * 4 + w;   // one node per wave
    const int b = node >> 10;
    const int m = node & (MM - 1);
    const int base = b * NN;
    const int c = (int)(__hip_atomic_load(&cnt[node], __ATOMIC_RELAXED,
                                          __HIP_MEMORY_SCOPE_AGENT) - s0);
    float sx = 0.f, sy = 0.f, sz = 0.f;

    if (c <= KSEL) {
        // members (one per lane) + (50-c) lowest-index non-members (all n<50)
        if (lane < c) {
            int n = lst[node * CAP + lane];
            float4 p = pt4[base + n];
            sx = p.x; sy = p.y; sz = p.z;
        }
        int k = KSEL - c;
        bool flag = (lane < KSEL) && (p2n[base + lane] != m);
        ull mask = __ballot(flag);
        int rank = __popcll(mask & ((1ULL << lane) - 1ULL));
        if (flag && rank < k) {
            float4 p = pt4[base + lane];
            sx += p.x; sy += p.y; sz += p.z;
        }
    } else if (c <= CAP) {
        // exact 50-smallest by (dist, idx) via parallel rank selection
        ull kv0 = ~0ULL, kv1 = ~0ULL, kv2 = ~0ULL, kv3 = ~0ULL;
        float4 pv0 = {0,0,0,0}, pv1 = {0,0,0,0}, pv2 = {0,0,0,0}, pv3 = {0,0,0,0};
        int s;
        s = lane;       if (s < c) { int n = lst[node*CAP+s]; pv0 = pt4[base+n]; kv0 = ((ull)fkey(pv0.w)<<32)|(unsigned int)n; skeys[w][s] = kv0; }
        s = lane + 64;  if (s < c) { int n = lst[node*CAP+s]; pv1 = pt4[base+n]; kv1 = ((ull)fkey(pv1.w)<<32)|(unsigned int)n; skeys[w][s] = kv1; }
        s = lane + 128; if (s < c) { int n = lst[node*CAP+s]; pv2 = pt4[base+n]; kv2 = ((ull)fkey(pv2.w)<<32)|(unsigned int)n; skeys[w][s] = kv2; }
        s = lane + 192; if (s < c) { int n = lst[node*CAP+s]; pv3 = pt4[base+n]; kv3 = ((ull)fkey(pv3.w)<<32)|(unsigned int)n; skeys[w][s] = kv3; }
        __asm__ volatile("s_waitcnt lgkmcnt(0)" ::: "memory");
        int r0 = 0, r1 = 0, r2 = 0, r3 = 0;
        for (int j = 0; j < c; ++j) {
            ull kj = skeys[w][j];              // broadcast read
            r0 += (kj < kv0); r1 += (kj < kv1); r2 += (kj < kv2); r3 += (kj < kv3);
        }
        if (r0 < KSEL) { sx += pv0.x; sy += pv0.y; sz += pv0.z; }
        if (r1 < KSEL) { sx += pv1.x; sy += pv1.y; sz += pv1.z; }
        if (r2 < KSEL) { sx += pv2.x; sy += pv2.y; sz += pv2.z; }
        if (r3 < KSEL) { sx += pv3.x; sy += pv3.y; sz += pv3.z; }
    } else {
        // pathological overflow backstop: serial extraction over full rescan
        ull last = 0ULL;
        int widx = -1;
        for (int r = 0; r < KSEL; ++r) {
            ull cand = ~0ULL;
            for (int n = lane; n < NN; n += 64) {
                if (p2n[base + n] == m) {
                    ull key = ((ull)fkey(pt4[base + n].w) << 32) | (unsigned int)n;
                    if (key > last) cand = umin64(cand, key);
                }
            }
            #pragma unroll
            for (int off = 32; off; off >>= 1)
                cand = umin64(cand, __shfl_xor(cand, off));
            last = cand;
            if (lane == r) widx = (int)(unsigned int)(cand & 0xFFFFFFFFULL);
        }
        if (widx >= 0) { float4 p = pt4[base+widx]; sx = p.x; sy = p.y; sz = p.z; }
    }

    #pragma unroll
    for (int off = 32; off; off >>= 1) {
        sx += __shfl_xor(sx, off);
        sy += __shfl_xor(sy, off);
        sz += __shfl_xor(sz, off);
    }
    if (lane == 0) {
        const float inv = 1.0f / (float)KSEL;
        float ex = sx * inv - kpw[node * 3 + 0];
        float ey = sy * inv - kpw[node * 3 + 1];
        float ez = sz * inv - kpw[node * 3 + 2];
        float wt = ow[node];
        red[w * 2]     = (fabsf(ex) + fabsf(ey) + fabsf(ez)) * wt;
        red[w * 2 + 1] = wt;
    }
    __syncthreads();
    if (tid == 0) {
        // device-scope atomics: coherent across XCDs
        atomicExch(&part[2 * blockIdx.x],     red[0] + red[2] + red[4] + red[6]);
        atomicExch(&part[2 * blockIdx.x + 1], red[1] + red[3] + red[5] + red[7]);
        __threadfence();
        unsigned int t = atomicAdd(done, 1u);
        *lastflag = ((int)(t - s0) == NODEBLK - 1);
    }
    __syncthreads();                 // lastflag is block-uniform after this
    if (*lastflag) {
        __threadfence();
        float v = 0.f, wt = 0.f;
        for (int i = tid; i < NODEBLK; i += 256) {
            v  += atomicAdd(&part[2 * i], 0.f);
            wt += atomicAdd(&part[2 * i + 1], 0.f);
        }
        #pragma unroll
        for (int off = 32; off; off >>= 1) {
            v  += __shfl_xor(v, off);
            wt += __shfl_xor(wt, off);
        }
        if (lane == 0) { red[w * 2] = v; red[w * 2 + 1] = wt; }
        __syncthreads();
        if (tid == 0)
            out[0] = (red[0] + red[2] + red[4] + red[6]) /
                     fmaxf(red[1] + red[3] + red[5] + red[7], 1e-6f);
    }
}

extern "C" void kernel_launch(void* const* d_in, const int* in_sizes, int n_in,
                              void* d_out, int out_size, void* d_ws, size_t ws_size,
                              hipStream_t stream) {
    const float* pts  = (const float*)d_in[0];  // B,N,3
    const float* kp   = (const float*)d_in[1];  // B,M,3
    const float* kpw  = (const float*)d_in[2];  // B,M,3
    const float* pose = (const float*)d_in[3];  // B,4,4
    const float* ow   = (const float*)d_in[4];  // B,M
    float* out = (float*)d_out;

    char* ws = (char*)d_ws;
    unsigned int* done = (unsigned int*)(ws + 0);
    unsigned int* sent = (unsigned int*)(ws + 4);   // untouched poison word
    unsigned int* bar  = (unsigned int*)(ws + 8);   // barrier ticket (starts poisoned)
    size_t off = 16;
    float* part = (float*)(ws + off);  off += (size_t)NODEBLK * 2 * 4;     // 8 KB
    unsigned int* cnt = (unsigned int*)(ws + off); off += (size_t)BB * MM * 4;
    int*    p2n = (int*)(ws + off);    off += (size_t)BB * NN * 4;
    float4* pt4 = (float4*)(ws + off); off += (size_t)BB * NN * 16;        // 1.28 MB
    int*    lst = (int*)(ws + off);    off += (size_t)BB * MM * CAP * 4;   // 4 MB

    k_fused<<<GRID1, 256, 0, stream>>>(pts, kp, pose, kpw, ow, sent,
                                       p2n, pt4, cnt, lst, part, done, bar, out);
}

// Round 4
// 227.217 us; speedup vs baseline: 1.1406x; 1.1406x over previous
//
#include <hip/hip_runtime.h>
#include <float.h>
#include <stdint.h>

#define BB 4
#define NN 20000
#define MM 1024
#define CAP 256
#define KSEL 50
#define UNITS 1252           // 313 point-tiles x 4 batches
#define GRID1 1024           // EXACTLY 4 blocks/CU x 256 CU = measured-safe co-residency
#define NODEBLK 1024         // node phase: 4 waves -> 1 node/wave

typedef unsigned long long ull;

// order-preserving float -> uint32 map (total order incl. negatives)
__device__ __forceinline__ unsigned int fkey(float d) {
    unsigned int u = __float_as_uint(d);
    return (u & 0x80000000u) ? ~u : (u | 0x80000000u);
}
__device__ __forceinline__ float fkey_inv(unsigned int h) {
    return (h & 0x80000000u) ? __uint_as_float(h ^ 0x80000000u)
                             : __uint_as_float(~h);
}
__device__ __forceinline__ ull umin64(ull a, ull b) { return a < b ? a : b; }

// Fused assign + node kernel, round 2 of the fusion experiment.
// R3 post-mortem: OccupancyPercent 51% == 4 blocks/CU resident (not the 5 the
// resource arithmetic promised) -> 1252 blocks were NOT co-resident -> the
// spin barrier resolved only via preemption/timeslicing (205 us). Fix: grid
// of exactly 1024 = 4/CU (measured packing, with margin: LDS 74/160 KB,
// 16/32 waves, VGPR 32). The 1252 phase-1 units are strided (u += 1024);
// 1024 % 4 == 0 keeps each block on ONE batch so kp stages once.
// Barrier protocol is bit-identical to R3 (passed, absmax 0.0).
__global__ __launch_bounds__(256, 4) void k_fused(
    const float* __restrict__ pts, const float* __restrict__ kp,
    const float* __restrict__ pose, const float* __restrict__ kpw,
    const float* __restrict__ ow, const unsigned int* __restrict__ sent,
    int* __restrict__ p2n, float4* __restrict__ pt4,
    unsigned int* __restrict__ cnt, int* __restrict__ lst,
    float* __restrict__ part, unsigned int* __restrict__ done,
    unsigned int* __restrict__ bar, float* __restrict__ out)
{
    // LDS union: phase1 {skp 16KB + skey 2KB}, phase3 {skeys 8KB + red/flag}
    __shared__ __align__(16) char smraw[18432];
    float4* skp = (float4*)smraw;                                       // ph1 [0,16384)
    ull (*skey)[64] = (ull (*)[64])(smraw + 16384);                     // ph1 [16384,18432)
    ull (*skeys)[CAP] = (ull (*)[CAP])smraw;                            // ph3 [0,8192)
    float* red = (float*)(smraw + 8192);                                // ph3 8 floats
    int* lastflag = (int*)(smraw + 8224);                               // ph3

    const unsigned int s0 = *sent;
    const int tid = threadIdx.x;
    const int w = tid >> 6, lane = tid & 63;

    // ---------------- phase 1: nearest-node assign (R1 body, unit-strided) --
    {
        const int b = blockIdx.x & 3;          // same b for u and u+1024

        for (int j = tid; j < MM; j += 256) {
            const float* kk = kp + ((size_t)b * MM + j) * 3;
            float x = kk[0], y = kk[1], z = kk[2];
            skp[j] = make_float4(-2.0f * x, -2.0f * y, -2.0f * z,
                                 x * x + y * y + z * z);   // (-2k, |k|^2)
        }
        __syncthreads();

        const float* pb = pts + (size_t)b * NN * 3;
        for (int u = blockIdx.x; u < UNITS; u += GRID1) {
            const int tile = u >> 2;
            const int n = tile * 64 + lane;
            const bool v = n < NN;
            float px = 0.f, py = 0.f, pz = 0.f;
            if (v) { px = pb[n * 3]; py = pb[n * 3 + 1]; pz = pb[n * 3 + 2]; }

            float best = FLT_MAX;
            int bi = 0;
            const int j0 = w * 256;            // wave's 256-kp sub-chunk
            #pragma unroll 8
            for (int j = 0; j < 256; ++j) {
                float4 q = skp[j0 + j];        // uniform broadcast ds_read_b128
                // d' = |k|^2 - 2*k.p : 3-fma chain, argmin-equiv (psq deferred)
                float d = fmaf(q.x, px, fmaf(q.y, py, fmaf(q.z, pz, q.w)));
                if (d < best) { best = d; bi = j0 + j; }   // strict <: first-min
            }
            skey[w][lane] = v ? (((ull)fkey(best) << 32) | (unsigned int)bi) : ~0ULL;
            __syncthreads();

            // wave 0 finishes point tile*64+tid (coords live in its own regs)
            if (tid < 64 && v) {
                ull kmin = skey[0][lane];
                #pragma unroll
                for (int ww = 1; ww < 4; ++ww) kmin = umin64(kmin, skey[ww][lane]);
                const int bi_g = (int)(unsigned int)(kmin & 0xFFFFFFFFULL);
                const float psq = fmaf(px, px, fmaf(py, py, pz * pz));
                const float bestd = fkey_inv((unsigned int)(kmin >> 32)) + psq;
                const float* P = pose + b * 16;
                float tx = P[0]*px + P[1]*py + P[2] *pz + P[3];
                float ty = P[4]*px + P[5]*py + P[6] *pz + P[7];
                float tz = P[8]*px + P[9]*py + P[10]*pz + P[11];
                const int g = b * NN + n;
                p2n[g] = bi_g;
                pt4[g] = make_float4(tx, ty, tz, bestd);
                const int node = b * MM + bi_g;
                unsigned int old = atomicAdd(&cnt[node], 1u);
                int s = (int)(old - s0);
                if (s >= 0 && s < CAP) lst[node * CAP + s] = n;
            }
            __syncthreads();                   // skey reused next unit
        }
    }

    // ---------------- device-wide barrier (1024 co-resident blocks) --------
    if (tid == 0) {
        __threadfence();                   // release: ph1 writes -> coherence point
        __hip_atomic_fetch_add(bar, 1u, __ATOMIC_RELEASE, __HIP_MEMORY_SCOPE_AGENT);
        while ((unsigned int)(__hip_atomic_load(bar, __ATOMIC_ACQUIRE,
                                                __HIP_MEMORY_SCOPE_AGENT) - s0) < GRID1)
            __builtin_amdgcn_s_sleep(8);
        __threadfence();                   // acquire: invalidate stale cache lines
    }
    __syncthreads();

    // ---------------- phase 3: per-node knn-mean + reduce (R1 body) --------
    const int node = blockIdx.x * 4 + w;   // one node per wave
    const int b = node >> 10;
    const int m = node & (MM - 1);
    const int base = b * NN;
    const int c = (int)(__hip_atomic_load(&cnt[node], __ATOMIC_RELAXED,
                                          __HIP_MEMORY_SCOPE_AGENT) - s0);
    float sx = 0.f, sy = 0.f, sz = 0.f;

    if (c <= KSEL) {
        // members (one per lane) + (50-c) lowest-index non-members (all n<50)
        if (lane < c) {
            int n = lst[node * CAP + lane];
            float4 p = pt4[base + n];
            sx = p.x; sy = p.y; sz = p.z;
        }
        int k = KSEL - c;
        bool flag = (lane < KSEL) && (p2n[base + lane] != m);
        ull mask = __ballot(flag);
        int rank = __popcll(mask & ((1ULL << lane) - 1ULL));
        if (flag && rank < k) {
            float4 p = pt4[base + lane];
            sx += p.x; sy += p.y; sz += p.z;
        }
    } else if (c <= CAP) {
        // exact 50-smallest by (dist, idx) via parallel rank selection
        ull kv0 = ~0ULL, kv1 = ~0ULL, kv2 = ~0ULL, kv3 = ~0ULL;
        float4 pv0 = {0,0,0,0}, pv1 = {0,0,0,0}, pv2 = {0,0,0,0}, pv3 = {0,0,0,0};
        int s;
        s = lane;       if (s < c) { int n = lst[node*CAP+s]; pv0 = pt4[base+n]; kv0 = ((ull)fkey(pv0.w)<<32)|(unsigned int)n; skeys[w][s] = kv0; }
        s = lane + 64;  if (s < c) { int n = lst[node*CAP+s]; pv1 = pt4[base+n]; kv1 = ((ull)fkey(pv1.w)<<32)|(unsigned int)n; skeys[w][s] = kv1; }
        s = lane + 128; if (s < c) { int n = lst[node*CAP+s]; pv2 = pt4[base+n]; kv2 = ((ull)fkey(pv2.w)<<32)|(unsigned int)n; skeys[w][s] = kv2; }
        s = lane + 192; if (s < c) { int n = lst[node*CAP+s]; pv3 = pt4[base+n]; kv3 = ((ull)fkey(pv3.w)<<32)|(unsigned int)n; skeys[w][s] = kv3; }
        __asm__ volatile("s_waitcnt lgkmcnt(0)" ::: "memory");
        int r0 = 0, r1 = 0, r2 = 0, r3 = 0;
        for (int j = 0; j < c; ++j) {
            ull kj = skeys[w][j];              // broadcast read
            r0 += (kj < kv0); r1 += (kj < kv1); r2 += (kj < kv2); r3 += (kj < kv3);
        }
        if (r0 < KSEL) { sx += pv0.x; sy += pv0.y; sz += pv0.z; }
        if (r1 < KSEL) { sx += pv1.x; sy += pv1.y; sz += pv1.z; }
        if (r2 < KSEL) { sx += pv2.x; sy += pv2.y; sz += pv2.z; }
        if (r3 < KSEL) { sx += pv3.x; sy += pv3.y; sz += pv3.z; }
    } else {
        // pathological overflow backstop: serial extraction over full rescan
        ull last = 0ULL;
        int widx = -1;
        for (int r = 0; r < KSEL; ++r) {
            ull cand = ~0ULL;
            for (int n = lane; n < NN; n += 64) {
                if (p2n[base + n] == m) {
                    ull key = ((ull)fkey(pt4[base + n].w) << 32) | (unsigned int)n;
                    if (key > last) cand = umin64(cand, key);
                }
            }
            #pragma unroll
            for (int off = 32; off; off >>= 1)
                cand = umin64(cand, __shfl_xor(cand, off));
            last = cand;
            if (lane == r) widx = (int)(unsigned int)(cand & 0xFFFFFFFFULL);
        }
        if (widx >= 0) { float4 p = pt4[base+widx]; sx = p.x; sy = p.y; sz = p.z; }
    }

    #pragma unroll
    for (int off = 32; off; off >>= 1) {
        sx += __shfl_xor(sx, off);
        sy += __shfl_xor(sy, off);
        sz += __shfl_xor(sz, off);
    }
    if (lane == 0) {
        const float inv = 1.0f / (float)KSEL;
        float ex = sx * inv - kpw[node * 3 + 0];
        float ey = sy * inv - kpw[node * 3 + 1];
        float ez = sz * inv - kpw[node * 3 + 2];
        float wt = ow[node];
        red[w * 2]     = (fabsf(ex) + fabsf(ey) + fabsf(ez)) * wt;
        red[w * 2 + 1] = wt;
    }
    __syncthreads();
    if (tid == 0) {
        // device-scope atomics: coherent across XCDs
        atomicExch(&part[2 * blockIdx.x],     red[0] + red[2] + red[4] + red[6]);
        atomicExch(&part[2 * blockIdx.x + 1], red[1] + red[3] + red[5] + red[7]);
        __threadfence();
        unsigned int t = atomicAdd(done, 1u);
        *lastflag = ((int)(t - s0) == NODEBLK - 1);
    }
    __syncthreads();                 // lastflag is block-uniform after this
    if (*lastflag) {
        __threadfence();
        float v = 0.f, wt = 0.f;
        for (int i = tid; i < NODEBLK; i += 256) {
            v  += atomicAdd(&part[2 * i], 0.f);
            wt += atomicAdd(&part[2 * i + 1], 0.f);
        }
        #pragma unroll
        for (int off = 32; off; off >>= 1) {
            v  += __shfl_xor(v, off);
            wt += __shfl_xor(wt, off);
        }
        if (lane == 0) { red[w * 2] = v; red[w * 2 + 1] = wt; }
        __syncthreads();
        if (tid == 0)
            out[0] = (red[0] + red[2] + red[4] + red[6]) /
                     fmaxf(red[1] + red[3] + red[5] + red[7], 1e-6f);
    }
}

extern "C" void kernel_launch(void* const* d_in, const int* in_sizes, int n_in,
                              void* d_out, int out_size, void* d_ws, size_t ws_size,
                              hipStream_t stream) {
    const float* pts  = (const float*)d_in[0];  // B,N,3
    const float* kp   = (const float*)d_in[1];  // B,M,3
    const float* kpw  = (const float*)d_in[2];  // B,M,3
    const float* pose = (const float*)d_in[3];  // B,4,4
    const float* ow   = (const float*)d_in[4];  // B,M
    float* out = (float*)d_out;

    char* ws = (char*)d_ws;
    unsigned int* done = (unsigned int*)(ws + 0);
    unsigned int* sent = (unsigned int*)(ws + 4);   // untouched poison word
    unsigned int* bar  = (unsigned int*)(ws + 8);   // barrier ticket (starts poisoned)
    size_t off = 16;
    float* part = (float*)(ws + off);  off += (size_t)NODEBLK * 2 * 4;     // 8 KB
    unsigned int* cnt = (unsigned int*)(ws + off); off += (size_t)BB * MM * 4;
    int*    p2n = (int*)(ws + off);    off += (size_t)BB * NN * 4;
    float4* pt4 = (float4*)(ws + off); off += (size_t)BB * NN * 16;        // 1.28 MB
    int*    lst = (int*)(ws + off);    off += (size_t)BB * MM * CAP * 4;   // 4 MB

    k_fused<<<GRID1, 256, 0, stream>>>(pts, kp, pose, kpw, ow, sent,
                                       p2n, pt4, cnt, lst, part, done, bar, out);
}

// Round 5
// 142.250 us; speedup vs baseline: 1.8219x; 1.5973x over previous
//
#include <hip/hip_runtime.h>
#include <float.h>
#include <stdint.h>

#define BB 4
#define NN 20000
#define MM 1024
#define CAP 256
#define KSEL 50
#define UNITS 1252           // 313 point-tiles x 4 batches
#define GRID1 1024           // 4 blocks/CU x 256 CU = measured-safe co-residency (R4)
#define NODEBLK 1024         // node phase: 4 waves -> 1 node/wave

typedef unsigned long long ull;

// order-preserving float -> uint32 map (total order incl. negatives)
__device__ __forceinline__ unsigned int fkey(float d) {
    unsigned int u = __float_as_uint(d);
    return (u & 0x80000000u) ? ~u : (u | 0x80000000u);
}
__device__ __forceinline__ float fkey_inv(unsigned int h) {
    return (h & 0x80000000u) ? __uint_as_float(h ^ 0x80000000u)
                             : __uint_as_float(~h);
}
__device__ __forceinline__ ull umin64(ull a, ull b) { return a < b ? a : b; }

// ---- agent-coherent (write-through, sc0|sc1) access helpers --------------
// R4 post-mortem: per-poll ACQUIRE loads in the spin emitted L2-invalidates
// (~170ns x participants, serialized at each XCD L2 -> 160+ us of idle).
// Instead: cross-phase data goes through the coherence point directly via
// relaxed agent-scope atomic ld/st (no wbl2/inv instructions anywhere in the
// barrier path).
__device__ __forceinline__ void cstore4(float4* a, float4 v) {
    union { float4 f; ull u[2]; } c; c.f = v;
    ull* p = (ull*)a;
    __hip_atomic_store(p,     c.u[0], __ATOMIC_RELAXED, __HIP_MEMORY_SCOPE_AGENT);
    __hip_atomic_store(p + 1, c.u[1], __ATOMIC_RELAXED, __HIP_MEMORY_SCOPE_AGENT);
}
__device__ __forceinline__ float4 cload4(const float4* a) {
    union { float4 f; ull u[2]; } c;
    const ull* p = (const ull*)a;
    c.u[0] = __hip_atomic_load(p,     __ATOMIC_RELAXED, __HIP_MEMORY_SCOPE_AGENT);
    c.u[1] = __hip_atomic_load(p + 1, __ATOMIC_RELAXED, __HIP_MEMORY_SCOPE_AGENT);
    return c.f;
}
__device__ __forceinline__ void cstore_i(int* a, int v) {
    __hip_atomic_store((unsigned*)a, (unsigned)v, __ATOMIC_RELAXED, __HIP_MEMORY_SCOPE_AGENT);
}
__device__ __forceinline__ int cload_i(const int* a) {
    return (int)__hip_atomic_load((const unsigned*)a, __ATOMIC_RELAXED, __HIP_MEMORY_SCOPE_AGENT);
}

__global__ __launch_bounds__(256, 4) void k_fused(
    const float* __restrict__ pts, const float* __restrict__ kp,
    const float* __restrict__ pose, const float* __restrict__ kpw,
    const float* __restrict__ ow, const unsigned int* __restrict__ sent,
    int* __restrict__ p2n, float4* __restrict__ pt4,
    unsigned int* __restrict__ cnt, int* __restrict__ lst,
    float* __restrict__ part, unsigned int* __restrict__ done,
    unsigned int* __restrict__ bar, float* __restrict__ out)
{
    // LDS union: phase1 {skp 16KB + skey 2KB}, phase3 {skeys 8KB + red/flag}
    __shared__ __align__(16) char smraw[18432];
    float4* skp = (float4*)smraw;                                       // ph1 [0,16384)
    ull (*skey)[64] = (ull (*)[64])(smraw + 16384);                     // ph1 [16384,18432)
    ull (*skeys)[CAP] = (ull (*)[CAP])smraw;                            // ph3 [0,8192)
    float* red = (float*)(smraw + 8192);                                // ph3 8 floats
    int* lastflag = (int*)(smraw + 8224);                               // ph3

    const unsigned int s0 = *sent;
    const int tid = threadIdx.x;
    const int w = tid >> 6, lane = tid & 63;

    // ---------------- phase 1: nearest-node assign (R1 body, unit-strided) --
    {
        const int b = blockIdx.x & 3;          // same b for u and u+1024

        for (int j = tid; j < MM; j += 256) {
            const float* kk = kp + ((size_t)b * MM + j) * 3;
            float x = kk[0], y = kk[1], z = kk[2];
            skp[j] = make_float4(-2.0f * x, -2.0f * y, -2.0f * z,
                                 x * x + y * y + z * z);   // (-2k, |k|^2)
        }
        __syncthreads();

        const float* pb = pts + (size_t)b * NN * 3;
        for (int u = blockIdx.x; u < UNITS; u += GRID1) {
            const int tile = u >> 2;
            const int n = tile * 64 + lane;
            const bool v = n < NN;
            float px = 0.f, py = 0.f, pz = 0.f;
            if (v) { px = pb[n * 3]; py = pb[n * 3 + 1]; pz = pb[n * 3 + 2]; }

            float best = FLT_MAX;
            int bi = 0;
            const int j0 = w * 256;            // wave's 256-kp sub-chunk
            #pragma unroll 8
            for (int j = 0; j < 256; ++j) {
                float4 q = skp[j0 + j];        // uniform broadcast ds_read_b128
                // d' = |k|^2 - 2*k.p : 3-fma chain, argmin-equiv (psq deferred)
                float d = fmaf(q.x, px, fmaf(q.y, py, fmaf(q.z, pz, q.w)));
                if (d < best) { best = d; bi = j0 + j; }   // strict <: first-min
            }
            skey[w][lane] = v ? (((ull)fkey(best) << 32) | (unsigned int)bi) : ~0ULL;
            __syncthreads();

            // wave 0 finishes point tile*64+tid (coords live in its own regs).
            // NOTE: every cross-phase store below is agent-coherent (write-
            // through) -> no cache flush needed at the barrier.
            if (tid < 64 && v) {
                ull kmin = skey[0][lane];
                #pragma unroll
                for (int ww = 1; ww < 4; ++ww) kmin = umin64(kmin, skey[ww][lane]);
                const int bi_g = (int)(unsigned int)(kmin & 0xFFFFFFFFULL);
                const float psq = fmaf(px, px, fmaf(py, py, pz * pz));
                const float bestd = fkey_inv((unsigned int)(kmin >> 32)) + psq;
                const float* P = pose + b * 16;
                float tx = P[0]*px + P[1]*py + P[2] *pz + P[3];
                float ty = P[4]*px + P[5]*py + P[6] *pz + P[7];
                float tz = P[8]*px + P[9]*py + P[10]*pz + P[11];
                const int g = b * NN + n;
                cstore_i(&p2n[g], bi_g);
                cstore4(&pt4[g], make_float4(tx, ty, tz, bestd));
                const int node = b * MM + bi_g;
                unsigned int old = atomicAdd(&cnt[node], 1u);   // coherence-point RMW
                int s = (int)(old - s0);
                if (s >= 0 && s < CAP) cstore_i(&lst[node * CAP + s], n);
            }
            __syncthreads();                   // skey reused next unit
        }
    }

    // ---------------- device-wide barrier: zero cache-maintenance ops ------
    // All phase-1 shared data already sits at the coherence point (write-
    // through stores + atomics). Ordering: all stores were issued by THIS
    // wave (wave 0 holds tid 0 and all storing lanes), so vmcnt(0) drains
    // them before the relaxed ticket add. Spin = relaxed agent loads (no
    // buffer_inv per poll -- R4's poison), s_sleep(64) to keep the shared
    // ticket line cool.
    __syncthreads();
    if (tid == 0) {
        __asm__ volatile("s_waitcnt vmcnt(0)" ::: "memory");
        __hip_atomic_fetch_add(bar, 1u, __ATOMIC_RELAXED, __HIP_MEMORY_SCOPE_AGENT);
        while ((unsigned int)(__hip_atomic_load(bar, __ATOMIC_RELAXED,
                                                __HIP_MEMORY_SCOPE_AGENT) - s0) < GRID1)
            __builtin_amdgcn_s_sleep(64);
    }
    __syncthreads();

    // ---------------- phase 3: per-node knn-mean + reduce (R1 body, ---------
    // ---------------- all shared-data reads agent-coherent) ----------------
    const int node = blockIdx.x * 4 + w;   // one node per wave
    const int b = node >> 10;
    const int m = node & (MM - 1);
    const int base = b * NN;
    const int c = (int)(__hip_atomic_load(&cnt[node], __ATOMIC_RELAXED,
                                          __HIP_MEMORY_SCOPE_AGENT) - s0);
    float sx = 0.f, sy = 0.f, sz = 0.f;

    if (c <= KSEL) {
        // members (one per lane) + (50-c) lowest-index non-members (all n<50)
        if (lane < c) {
            int n = cload_i(&lst[node * CAP + lane]);
            float4 p = cload4(&pt4[base + n]);
            sx = p.x; sy = p.y; sz = p.z;
        }
        int k = KSEL - c;
        bool flag = (lane < KSEL) && (cload_i(&p2n[base + lane]) != m);
        ull mask = __ballot(flag);
        int rank = __popcll(mask & ((1ULL << lane) - 1ULL));
        if (flag && rank < k) {
            float4 p = cload4(&pt4[base + lane]);
            sx += p.x; sy += p.y; sz += p.z;
        }
    } else if (c <= CAP) {
        // exact 50-smallest by (dist, idx) via parallel rank selection
        ull kv0 = ~0ULL, kv1 = ~0ULL, kv2 = ~0ULL, kv3 = ~0ULL;
        float4 pv0 = {0,0,0,0}, pv1 = {0,0,0,0}, pv2 = {0,0,0,0}, pv3 = {0,0,0,0};
        int s;
        s = lane;       if (s < c) { int n = cload_i(&lst[node*CAP+s]); pv0 = cload4(&pt4[base+n]); kv0 = ((ull)fkey(pv0.w)<<32)|(unsigned int)n; skeys[w][s] = kv0; }
        s = lane + 64;  if (s < c) { int n = cload_i(&lst[node*CAP+s]); pv1 = cload4(&pt4[base+n]); kv1 = ((ull)fkey(pv1.w)<<32)|(unsigned int)n; skeys[w][s] = kv1; }
        s = lane + 128; if (s < c) { int n = cload_i(&lst[node*CAP+s]); pv2 = cload4(&pt4[base+n]); kv2 = ((ull)fkey(pv2.w)<<32)|(unsigned int)n; skeys[w][s] = kv2; }
        s = lane + 192; if (s < c) { int n = cload_i(&lst[node*CAP+s]); pv3 = cload4(&pt4[base+n]); kv3 = ((ull)fkey(pv3.w)<<32)|(unsigned int)n; skeys[w][s] = kv3; }
        __asm__ volatile("s_waitcnt lgkmcnt(0)" ::: "memory");
        int r0 = 0, r1 = 0, r2 = 0, r3 = 0;
        for (int j = 0; j < c; ++j) {
            ull kj = skeys[w][j];              // broadcast read
            r0 += (kj < kv0); r1 += (kj < kv1); r2 += (kj < kv2); r3 += (kj < kv3);
        }
        if (r0 < KSEL) { sx += pv0.x; sy += pv0.y; sz += pv0.z; }
        if (r1 < KSEL) { sx += pv1.x; sy += pv1.y; sz += pv1.z; }
        if (r2 < KSEL) { sx += pv2.x; sy += pv2.y; sz += pv2.z; }
        if (r3 < KSEL) { sx += pv3.x; sy += pv3.y; sz += pv3.z; }
    } else {
        // pathological overflow backstop: serial extraction over full rescan
        ull last = 0ULL;
        int widx = -1;
        for (int r = 0; r < KSEL; ++r) {
            ull cand = ~0ULL;
            for (int n = lane; n < NN; n += 64) {
                if (cload_i(&p2n[base + n]) == m) {
                    float4 p = cload4(&pt4[base + n]);
                    ull key = ((ull)fkey(p.w) << 32) | (unsigned int)n;
                    if (key > last) cand = umin64(cand, key);
                }
            }
            #pragma unroll
            for (int off = 32; off; off >>= 1)
                cand = umin64(cand, __shfl_xor(cand, off));
            last = cand;
            if (lane == r) widx = (int)(unsigned int)(cand & 0xFFFFFFFFULL);
        }
        if (widx >= 0) { float4 p = cload4(&pt4[base+widx]); sx = p.x; sy = p.y; sz = p.z; }
    }

    #pragma unroll
    for (int off = 32; off; off >>= 1) {
        sx += __shfl_xor(sx, off);
        sy += __shfl_xor(sy, off);
        sz += __shfl_xor(sz, off);
    }
    if (lane == 0) {
        const float inv = 1.0f / (float)KSEL;
        float ex = sx * inv - kpw[node * 3 + 0];
        float ey = sy * inv - kpw[node * 3 + 1];
        float ez = sz * inv - kpw[node * 3 + 2];
        float wt = ow[node];
        red[w * 2]     = (fabsf(ex) + fabsf(ey) + fabsf(ez)) * wt;
        red[w * 2 + 1] = wt;
    }
    __syncthreads();
    if (tid == 0) {
        // device-scope atomics: coherent across XCDs (R1-proven epilogue)
        atomicExch(&part[2 * blockIdx.x],     red[0] + red[2] + red[4] + red[6]);
        atomicExch(&part[2 * blockIdx.x + 1], red[1] + red[3] + red[5] + red[7]);
        __threadfence();
        unsigned int t = atomicAdd(done, 1u);
        *lastflag = ((int)(t - s0) == NODEBLK - 1);
    }
    __syncthreads();                 // lastflag is block-uniform after this
    if (*lastflag) {
        __threadfence();
        float v = 0.f, wt = 0.f;
        for (int i = tid; i < NODEBLK; i += 256) {
            v  += atomicAdd(&part[2 * i], 0.f);
            wt += atomicAdd(&part[2 * i + 1], 0.f);
        }
        #pragma unroll
        for (int off = 32; off; off >>= 1) {
            v  += __shfl_xor(v, off);
            wt += __shfl_xor(wt, off);
        }
        if (lane == 0) { red[w * 2] = v; red[w * 2 + 1] = wt; }
        __syncthreads();
        if (tid == 0)
            out[0] = (red[0] + red[2] + red[4] + red[6]) /
                     fmaxf(red[1] + red[3] + red[5] + red[7], 1e-6f);
    }
}

extern "C" void kernel_launch(void* const* d_in, const int* in_sizes, int n_in,
                              void* d_out, int out_size, void* d_ws, size_t ws_size,
                              hipStream_t stream) {
    const float* pts  = (const float*)d_in[0];  // B,N,3
    const float* kp   = (const float*)d_in[1];  // B,M,3
    const float* kpw  = (const float*)d_in[2];  // B,M,3
    const float* pose = (const float*)d_in[3];  // B,4,4
    const float* ow   = (const float*)d_in[4];  // B,M
    float* out = (float*)d_out;

    char* ws = (char*)d_ws;
    unsigned int* done = (unsigned int*)(ws + 0);
    unsigned int* sent = (unsigned int*)(ws + 4);   // untouched poison word
    unsigned int* bar  = (unsigned int*)(ws + 8);   // barrier ticket (starts poisoned)
    size_t off = 16;
    float* part = (float*)(ws + off);  off += (size_t)NODEBLK * 2 * 4;     // 8 KB
    unsigned int* cnt = (unsigned int*)(ws + off); off += (size_t)BB * MM * 4;
    int*    p2n = (int*)(ws + off);    off += (size_t)BB * NN * 4;
    float4* pt4 = (float4*)(ws + off); off += (size_t)BB * NN * 16;        // 1.28 MB
    int*    lst = (int*)(ws + off);    off += (size_t)BB * MM * CAP * 4;   // 4 MB

    k_fused<<<GRID1, 256, 0, stream>>>(pts, kp, pose, kpw, ow, sent,
                                       p2n, pt4, cnt, lst, part, done, bar, out);
}

// Round 6
// 101.897 us; speedup vs baseline: 2.5434x; 1.3960x over previous
//
#include <hip/hip_runtime.h>
#include <float.h>
#include <stdint.h>

#define BB 4
#define NN 20000
#define MM 1024
#define CAP 256
#define KSEL 50
#define ABLK 256            // k_assign threads = 4 waves
#define PTS_PER_BLK 64      // points per k_assign block (1 per lane)
#define KW 256              // keypoints per wave (4 waves x 256 = 1024)
#define NODEBLK 1024        // k_node blocks: 4 waves each -> 1 node per wave

typedef unsigned long long ull;

// order-preserving float -> uint32 map (total order incl. negatives)
__device__ __forceinline__ unsigned int fkey(float d) {
    unsigned int u = __float_as_uint(d);
    return (u & 0x80000000u) ? ~u : (u | 0x80000000u);
}
__device__ __forceinline__ float fkey_inv(unsigned int h) {
    return (h & 0x80000000u) ? __uint_as_float(h ^ 0x80000000u)
                             : __uint_as_float(~h);
}
__device__ __forceinline__ ull umin64(ull a, ull b) { return a < b ? a : b; }

// R1-proven structure (102.8 us, absmax 0.0). R3-R5 established that in-kernel
// global barriers cost ~78-190 us on this part (single-line ticket contention
// at the coherence point) -- fusion abandoned; kernel boundary = the barrier.
// One change vs R1: VALUE-INLINING. Phase 1 writes the finished float4
// (tx,ty,tz,dist) into val4[node*CAP+slot] alongside lst[..]=n, so k_node's
// fast paths load val4[slot] and lst[slot] INDEPENDENTLY (one L2-latency
// round) instead of the dependent lst->pt4 chain (two rounds).
__global__ __launch_bounds__(ABLK) void k_assign(
    const float* __restrict__ pts, const float* __restrict__ kp,
    const float* __restrict__ pose, const unsigned int* __restrict__ sent,
    int* __restrict__ p2n, float4* __restrict__ pt4,
    unsigned int* __restrict__ cnt, int* __restrict__ lst,
    float4* __restrict__ val4)
{
    __shared__ float4 skp[MM];                               // 16 KB
    __shared__ ull skey[4][PTS_PER_BLK];                     // 2 KB
    const int b   = blockIdx.y;
    const int tid = threadIdx.x;

    for (int j = tid; j < MM; j += ABLK) {
        const float* kk = kp + ((size_t)b * MM + j) * 3;
        float x = kk[0], y = kk[1], z = kk[2];
        skp[j] = make_float4(-2.0f * x, -2.0f * y, -2.0f * z,
                             x * x + y * y + z * z);   // (-2k, |k|^2)
    }
    __syncthreads();

    const int w = tid >> 6, lane = tid & 63;
    const int pbase = blockIdx.x * PTS_PER_BLK;
    const int n = pbase + lane;
    const bool v = n < NN;
    const float* pb = pts + (size_t)b * NN * 3;
    float px = 0.f, py = 0.f, pz = 0.f;
    if (v) { px = pb[n * 3]; py = pb[n * 3 + 1]; pz = pb[n * 3 + 2]; }

    float best = FLT_MAX;
    int bi = 0;
    const int j0 = w * KW;
    #pragma unroll 8
    for (int j = 0; j < KW; ++j) {
        float4 q = skp[j0 + j];                 // uniform broadcast ds_read_b128
        // d' = |k|^2 - 2*k.p : 3-fma chain, argmin-equiv (psq deferred)
        float d = fmaf(q.x, px, fmaf(q.y, py, fmaf(q.z, pz, q.w)));
        if (d < best) { best = d; bi = j0 + j; }   // strict < : first-min
    }
    skey[w][lane] = v ? (((ull)fkey(best) << 32) | (unsigned int)bi) : ~0ULL;
    __syncthreads();

    // wave 0 finishes point pbase+tid (coords live in this thread's regs)
    if (tid < PTS_PER_BLK && v) {
        ull kmin = skey[0][lane];
        #pragma unroll
        for (int ww = 1; ww < 4; ++ww) kmin = umin64(kmin, skey[ww][lane]);
        const int bi_g = (int)(unsigned int)(kmin & 0xFFFFFFFFULL);
        const float psq = fmaf(px, px, fmaf(py, py, pz * pz));
        const float bestd = fkey_inv((unsigned int)(kmin >> 32)) + psq; // true sq_dist
        const float* P = pose + b * 16;
        float tx = P[0]*px + P[1]*py + P[2] *pz + P[3];
        float ty = P[4]*px + P[5]*py + P[6] *pz + P[7];
        float tz = P[8]*px + P[9]*py + P[10]*pz + P[11];
        const float4 pv = make_float4(tx, ty, tz, bestd);
        const int g = b * NN + n;
        p2n[g] = bi_g;
        pt4[g] = pv;                              // one dwordx4 store
        const int node = b * MM + bi_g;
        unsigned int old = atomicAdd(&cnt[node], 1u);
        int s = (int)(old - *sent);
        if (s >= 0 && s < CAP) {
            lst[node * CAP + s]  = n;             // index (tie-break key)
            val4[node * CAP + s] = pv;            // value-inlined coords+dist
        }
    }
}

// one WAVE per node (4096 waves). Fast paths use val4 (independent loads, one
// latency round). Slow path = exact rank selection. Per-block partials +
// ticket: last block reduces + writes out.
__global__ __launch_bounds__(256) void k_node(
    const int* __restrict__ p2n, const float4* __restrict__ pt4,
    const unsigned int* __restrict__ cnt, const int* __restrict__ lst,
    const float4* __restrict__ val4,
    const float* __restrict__ kpw, const float* __restrict__ ow,
    const unsigned int* __restrict__ sent,
    float* __restrict__ part, unsigned int* __restrict__ done,
    float* __restrict__ out)
{
    __shared__ ull skeys[4][CAP];                  // 8 KB, per-wave segments
    __shared__ float red[8];
    __shared__ int lastflag;

    const unsigned int s0 = *sent;
    const int lane = threadIdx.x & 63;
    const int wid  = threadIdx.x >> 6;
    const int node = blockIdx.x * 4 + wid;         // exactly one node per wave
    const int b = node >> 10;
    const int m = node & (MM - 1);
    const int base = b * NN;
    const int c = (int)(cnt[node] - s0);
    float sx = 0.f, sy = 0.f, sz = 0.f;

    if (c <= KSEL) {
        // members (one per lane, value-inlined: NO dependent load)
        if (lane < c) {
            float4 p = val4[node * CAP + lane];
            sx = p.x; sy = p.y; sz = p.z;
        }
        // + (50-c) lowest-index non-members (all n<50)
        int k = KSEL - c;
        bool flag = (lane < KSEL) && (p2n[base + lane] != m);
        ull mask = __ballot(flag);
        int rank = __popcll(mask & ((1ULL << lane) - 1ULL));
        if (flag && rank < k) {
            float4 p = pt4[base + lane];
            sx += p.x; sy += p.y; sz += p.z;
        }
    } else if (c <= CAP) {
        // exact 50-smallest by (dist, idx) via parallel rank selection:
        // keys unique (idx in low bits) -> exactly 50 keys have rank < 50.
        // lst[s] and val4[s] are INDEPENDENT loads (no pointer chase).
        ull kv0 = ~0ULL, kv1 = ~0ULL, kv2 = ~0ULL, kv3 = ~0ULL;
        float4 pv0 = {0,0,0,0}, pv1 = {0,0,0,0}, pv2 = {0,0,0,0}, pv3 = {0,0,0,0};
        int s;
        s = lane;       if (s < c) { int n = lst[node*CAP+s]; pv0 = val4[node*CAP+s]; kv0 = ((ull)fkey(pv0.w)<<32)|(unsigned int)n; skeys[wid][s] = kv0; }
        s = lane + 64;  if (s < c) { int n = lst[node*CAP+s]; pv1 = val4[node*CAP+s]; kv1 = ((ull)fkey(pv1.w)<<32)|(unsigned int)n; skeys[wid][s] = kv1; }
        s = lane + 128; if (s < c) { int n = lst[node*CAP+s]; pv2 = val4[node*CAP+s]; kv2 = ((ull)fkey(pv2.w)<<32)|(unsigned int)n; skeys[wid][s] = kv2; }
        s = lane + 192; if (s < c) { int n = lst[node*CAP+s]; pv3 = val4[node*CAP+s]; kv3 = ((ull)fkey(pv3.w)<<32)|(unsigned int)n; skeys[wid][s] = kv3; }
        // same-wave LDS write->read: drain lgkm, block compiler reordering
        __asm__ volatile("s_waitcnt lgkmcnt(0)" ::: "memory");
        int r0 = 0, r1 = 0, r2 = 0, r3 = 0;
        for (int j = 0; j < c; ++j) {
            ull kj = skeys[wid][j];              // broadcast read
            r0 += (kj < kv0); r1 += (kj < kv1); r2 += (kj < kv2); r3 += (kj < kv3);
        }
        // invalid keys (~0ULL) have rank >= c > 50: never selected
        if (r0 < KSEL) { sx += pv0.x; sy += pv0.y; sz += pv0.z; }
        if (r1 < KSEL) { sx += pv1.x; sy += pv1.y; sz += pv1.z; }
        if (r2 < KSEL) { sx += pv2.x; sy += pv2.y; sz += pv2.z; }
        if (r3 < KSEL) { sx += pv3.x; sy += pv3.y; sz += pv3.z; }
    } else {
        // pathological overflow backstop: serial extraction over full rescan
        ull last = 0ULL;
        int widx = -1;
        for (int r = 0; r < KSEL; ++r) {
            ull cand = ~0ULL;
            for (int n = lane; n < NN; n += 64) {
                if (p2n[base + n] == m) {
                    ull key = ((ull)fkey(pt4[base + n].w) << 32) | (unsigned int)n;
                    if (key > last) cand = umin64(cand, key);
                }
            }
            #pragma unroll
            for (int off = 32; off; off >>= 1)
                cand = umin64(cand, __shfl_xor(cand, off));
            last = cand;
            if (lane == r) widx = (int)(unsigned int)(cand & 0xFFFFFFFFULL);
        }
        if (widx >= 0) { float4 p = pt4[base+widx]; sx = p.x; sy = p.y; sz = p.z; }
    }

    #pragma unroll
    for (int off = 32; off; off >>= 1) {
        sx += __shfl_xor(sx, off);
        sy += __shfl_xor(sy, off);
        sz += __shfl_xor(sz, off);
    }
    if (lane == 0) {
        const float inv = 1.0f / (float)KSEL;
        float ex = sx * inv - kpw[node * 3 + 0];
        float ey = sy * inv - kpw[node * 3 + 1];
        float ez = sz * inv - kpw[node * 3 + 2];
        float w = ow[node];
        red[wid * 2]     = (fabsf(ex) + fabsf(ey) + fabsf(ez)) * w;
        red[wid * 2 + 1] = w;
    }
    __syncthreads();
    if (threadIdx.x == 0) {
        // device-scope atomics: coherent across XCDs
        atomicExch(&part[2 * blockIdx.x],     red[0] + red[2] + red[4] + red[6]);
        atomicExch(&part[2 * blockIdx.x + 1], red[1] + red[3] + red[5] + red[7]);
        __threadfence();
        unsigned int t = atomicAdd(done, 1u);
        lastflag = ((int)(t - s0) == NODEBLK - 1);
    }
    __syncthreads();                 // lastflag is block-uniform after this
    if (lastflag) {
        __threadfence();
        float v = 0.f, w = 0.f;
        for (int i = threadIdx.x; i < NODEBLK; i += 256) {
            v += atomicAdd(&part[2 * i], 0.f);
            w += atomicAdd(&part[2 * i + 1], 0.f);
        }
        #pragma unroll
        for (int off = 32; off; off >>= 1) {
            v += __shfl_xor(v, off);
            w += __shfl_xor(w, off);
        }
        if (lane == 0) { red[wid * 2] = v; red[wid * 2 + 1] = w; }
        __syncthreads();
        if (threadIdx.x == 0)
            out[0] = (red[0] + red[2] + red[4] + red[6]) /
                     fmaxf(red[1] + red[3] + red[5] + red[7], 1e-6f);
    }
}

extern "C" void kernel_launch(void* const* d_in, const int* in_sizes, int n_in,
                              void* d_out, int out_size, void* d_ws, size_t ws_size,
                              hipStream_t stream) {
    const float* pts  = (const float*)d_in[0];  // B,N,3
    const float* kp   = (const float*)d_in[1];  // B,M,3
    const float* kpw  = (const float*)d_in[2];  // B,M,3
    const float* pose = (const float*)d_in[3];  // B,4,4
    const float* ow   = (const float*)d_in[4];  // B,M
    float* out = (float*)d_out;

    char* ws = (char*)d_ws;
    size_t off = 0;
    unsigned int* done = (unsigned int*)(ws + off); off += 4;
    unsigned int* sent = (unsigned int*)(ws + off); off += 12;   // untouched poison word
    float* part = (float*)(ws + off);  off += (size_t)NODEBLK * 2 * 4;     // 8 KB
    unsigned int* cnt = (unsigned int*)(ws + off); off += (size_t)BB * MM * 4;
    int*    p2n = (int*)(ws + off);    off += (size_t)BB * NN * 4;
    float4* pt4 = (float4*)(ws + off); off += (size_t)BB * NN * 16;        // 1.28 MB
    int*    lst = (int*)(ws + off);    off += (size_t)BB * MM * CAP * 4;   // 4 MB
    float4* val4 = (float4*)(ws + off); off += (size_t)BB * MM * CAP * 16; // 16 MB

    dim3 g1((NN + PTS_PER_BLK - 1) / PTS_PER_BLK, BB);   // (313, 4)
    k_assign<<<g1, ABLK, 0, stream>>>(pts, kp, pose, sent, p2n, pt4, cnt, lst, val4);
    k_node<<<NODEBLK, 256, 0, stream>>>(p2n, pt4, cnt, lst, val4, kpw, ow, sent,
                                        part, done, out);
}